// Round 4
// baseline (312.060 us; speedup 1.0000x reference)
//
#include <hip/hip_runtime.h>

typedef __attribute__((ext_vector_type(8))) short short8;
typedef __attribute__((ext_vector_type(4))) float f32x4;

#define MFMA16(a, b, c) __builtin_amdgcn_mfma_f32_16x16x32_bf16(a, b, c, 0, 0, 0)

// Problem constants
#define BATCH 2
#define SEQ 2048
#define DMODEL 1024
#define NHEADS 16
#define HDIM 64
#define MROWS (BATCH * SEQ)      // 4096
#define N_QKV (3 * DMODEL)       // 3072

// softmax scale 1/sqrt(64) folded with log2(e) into Q at projection time,
// so attention logits are already in the exp2 domain.
#define QSCALE 0.1803368801111184f

// global->LDS direct DMA, 16B/lane, dest = wave-uniform base + lane*16 (m97/m104)
#define GLDS16(gp, lp)                                                       \
  __builtin_amdgcn_global_load_lds(                                          \
      (const __attribute__((address_space(1))) void*)(gp),                   \
      (__attribute__((address_space(3))) void*)(lp), 16, 0, 0)

static __device__ __forceinline__ unsigned short f2bf(float f) {
  unsigned int u = __float_as_uint(f);
  u = (u + 0x7fff + ((u >> 16) & 1)) >> 16;   // round-to-nearest-even
  return (unsigned short)u;
}

static __device__ __forceinline__ unsigned int pk2bf(float lo, float hi) {
  unsigned int r;
  asm("v_cvt_pk_bf16_f32 %0, %1, %2" : "=v"(r) : "v"(lo), "v"(hi));
  return r;
}

// raw hardware exp2 (single v_exp_f32; bypasses OCML's ~12-inst range checks)
static __device__ __forceinline__ float fexp2(float x) {
  float r;
  asm("v_exp_f32 %0, %1" : "=v"(r) : "v"(x));
  return r;
}

// ---------------------------------------------------------------- cvt fp32->bf16 (x, w_qkv, w_o fused)
__global__ void cvt3_kernel(const float* __restrict__ a, unsigned short* __restrict__ oa,
                            int na4, const float* __restrict__ b,
                            unsigned short* __restrict__ ob, int nb4,
                            const float* __restrict__ c,
                            unsigned short* __restrict__ oc, int nc4) {
  int i = blockIdx.x * blockDim.x + threadIdx.x;
  const float* src;
  unsigned short* dst;
  int j = i;
  if (j < na4) {
    src = a; dst = oa;
  } else if ((j -= na4) < nb4) {
    src = b; dst = ob;
  } else if ((j -= nb4) < nc4) {
    src = c; dst = oc;
  } else
    return;
  f32x4 v = ((const f32x4*)src)[j];
  ushort4 o;
  o.x = f2bf(v[0]); o.y = f2bf(v[1]); o.z = f2bf(v[2]); o.w = f2bf(v[3]);
  ((ushort4*)dst)[j] = o;
}

// ---------------------------------------------------------------- mask -> bitmask
__global__ void mask_to_bits(const int* __restrict__ mask,
                             unsigned int* __restrict__ bits) {
  int i = blockIdx.x * blockDim.x + threadIdx.x;   // 0 .. 2048*64-1
  const int* p = mask + (size_t)i * 32;
  unsigned int v = 0;
#pragma unroll
  for (int b = 0; b < 32; ++b) v |= (p[b] != 0 ? 1u : 0u) << b;
  bits[i] = v;
}

// ---------------------------------------------------------------- NT GEMM, 128x128 tile
// C[M,N] = A[M,K] * B[N,K]^T + bias[N]
template <int EPI>
__global__ __launch_bounds__(256) void gemm_bt(
    const unsigned short* __restrict__ A, const unsigned short* __restrict__ Bm,
    const float* __restrict__ bias, int Kdim, int Ndim,
    unsigned short* __restrict__ qb, unsigned short* __restrict__ kb,
    unsigned short* __restrict__ vtb, float* __restrict__ Cout) {
  __shared__ __align__(16) unsigned short lA[128 * 40];
  __shared__ __align__(16) unsigned short lB[128 * 40];

  int t = threadIdx.x;
  int m0 = blockIdx.y * 128, n0 = blockIdx.x * 128;
  int w = t >> 6, lane = t & 63, quad = lane >> 4, l16 = lane & 15;
  int wm = (w >> 1) * 64, wn = (w & 1) * 64;

  f32x4 acc[4][4];
#pragma unroll
  for (int i = 0; i < 4; ++i)
#pragma unroll
    for (int j = 0; j < 4; ++j) acc[i][j] = (f32x4){0.f, 0.f, 0.f, 0.f};

  int nK = Kdim >> 5;
  for (int kk = 0; kk < nK; ++kk) {
    __syncthreads();
#pragma unroll
    for (int c = 0; c < 2; ++c) {
      int id = t + c * 256;
      int row = id >> 2, c8 = (id & 3) << 3;
      *(uint4*)&lA[row * 40 + c8] =
          *(const uint4*)&A[(size_t)(m0 + row) * Kdim + (kk << 5) + c8];
      *(uint4*)&lB[row * 40 + c8] =
          *(const uint4*)&Bm[(size_t)(n0 + row) * Kdim + (kk << 5) + c8];
    }
    __syncthreads();
    short8 af[4], bfr[4];
#pragma unroll
    for (int i = 0; i < 4; ++i)
      af[i] = *(const short8*)&lA[(wm + i * 16 + l16) * 40 + quad * 8];
#pragma unroll
    for (int j = 0; j < 4; ++j)
      bfr[j] = *(const short8*)&lB[(wn + j * 16 + l16) * 40 + quad * 8];
#pragma unroll
    for (int i = 0; i < 4; ++i)
#pragma unroll
      for (int j = 0; j < 4; ++j) acc[i][j] = MFMA16(af[i], bfr[j], acc[i][j]);
  }

#pragma unroll
  for (int j = 0; j < 4; ++j) {
    int n = n0 + wn + j * 16 + l16;
    float bs = bias[n];
#pragma unroll
    for (int i = 0; i < 4; ++i) {
#pragma unroll
      for (int r = 0; r < 4; ++r) {
        int m = m0 + wm + i * 16 + quad * 4 + r;
        float v = acc[i][j][r] + bs;
        if (EPI == 0) {
          int b = m >> 11, s = m & 2047;
          int h = n / 192, rr = n % 192;
          int bh = (b << 4) + h;
          if (rr < 64)
            qb[((size_t)bh * SEQ + s) * HDIM + rr] = f2bf(v * QSCALE);
          else if (rr < 128)
            kb[((size_t)bh * SEQ + s) * HDIM + (rr - 64)] = f2bf(v);
          else
            vtb[((size_t)bh * HDIM + (rr - 128)) * SEQ + s] = f2bf(v);
        } else {
          Cout[(size_t)m * Ndim + n] = v;
        }
      }
    }
  }
}

// ---------------------------------------------------------------- flash attention
// grid: 1024 blocks (32 q-tiles of 64 rows x 32 bh), block 256 = 4 waves; wave
// owns 16 q-rows. Swapped-operand scheme: S^T = mfma(K, Q), O^T = mfma(V^T, P).
// VALU diet: raw v_exp_f32; denominator li accumulated by an all-ones MFMA
// (every output row of mfma(ones, P) = sum_k P[k][q] -> zero shuffles);
// max tree in v_max3 triples. V is NOT staged: per-XCD working set ~2MB is
// L2-resident (FETCH=14MB proved it), so V fragments load straight from L2,
// halving LDS-pipe traffic and shrinking LDS to 24KB. K stays LDS-staged
// (shared by 4 waves), double-buffered via global_load_lds, XOR-swizzled src.
__global__ __launch_bounds__(256, 4) void attn_kernel(
    const unsigned short* __restrict__ qbuf, const unsigned short* __restrict__ kbuf,
    const unsigned short* __restrict__ vtbuf, const unsigned int* __restrict__ mbits,
    unsigned short* __restrict__ ctx) {
  __shared__ __align__(16) unsigned short lK[2][64 * 64];
  __shared__ __align__(16) unsigned short lP[64 * 64];      // [q][key], per-wave rows

  // XCD-aware swizzle: cluster the 32 q-tiles of ~4 bh per XCD (1024 = 8*128)
  int lin = blockIdx.y * gridDim.x + blockIdx.x;
  int slin = (lin & 7) * 128 + (lin >> 3);
  int qt = slin & 31, bh = slin >> 5;
  int q0 = qt * 64;
  const unsigned short* Q = qbuf + (size_t)bh * SEQ * HDIM;
  const unsigned short* K = kbuf + (size_t)bh * SEQ * HDIM;
  const unsigned short* VT = vtbuf + (size_t)bh * HDIM * SEQ;

  int t = threadIdx.x;
  int w = t >> 6, lane = t & 63, quad = lane >> 4, l16 = lane & 15;
  int swz = (l16 & 7) << 4;          // byte-XOR swizzle for rows this lane reads

  // Q fragments in registers (scale*log2e pre-folded at projection)
  int qrow = q0 + w * 16 + l16;      // 0..2047
  short8 qf0 = *(const short8*)&Q[(size_t)qrow * HDIM + quad * 8];
  short8 qf1 = *(const short8*)&Q[(size_t)qrow * HDIM + 32 + quad * 8];

  // all-ones bf16 A-operand for the denominator MFMA
  const short one = (short)0x3F80;
  short8 ones = {one, one, one, one, one, one, one, one};

  f32x4 o[4];
#pragma unroll
  for (int jt = 0; jt < 4; ++jt) o[jt] = (f32x4){0.f, 0.f, 0.f, 0.f};
  f32x4 li4 = (f32x4){0.f, 0.f, 0.f, 0.f};   // all 4 regs == running denom
  // mi=0 is safe: logits ~ N(0, ~1.2) in log2 domain; exp2(s-0) can't overflow.
  float mi = 0.f;

  // K staging: wave w stages rows {w*8.., 32+w*8..}; global col pre-swizzled
  // so the linear LDS dest ends up XOR-swizzled (m173).
  int scol = ((lane & 7) ^ (lane >> 3)) << 3;   // shorts; srow&7 == lane>>3
  const unsigned short* gK = K + (size_t)(w * 8 + (lane >> 3)) * HDIM + scol;

#define STAGE_K(buf)                                             \
  do {                                                           \
    GLDS16(gK, &lK[buf][(w * 8) * 64]);                          \
    GLDS16(gK + 32 * HDIM, &lK[buf][(32 + w * 8) * 64]);         \
  } while (0)

  STAGE_K(0);
  gK += 64 * HDIM;

  // V fragment base: lane covers d-row (jt*16 + l16), keys (kh*32 + quad*8 ..)
  const unsigned short* gV = VT + (size_t)l16 * SEQ + quad * 8;

  const unsigned int* mrow = mbits + (size_t)qrow * 64;
  unsigned short* lPr = &lP[(w * 16 + l16) * 64];

  for (int it = 0; it < SEQ / 64; ++it) {
    __syncthreads();   // drains vmcnt -> K tile `it` staged; prev reads done
    if (it + 1 < SEQ / 64) {         // prefetch next K tile into other half
      STAGE_K((it + 1) & 1);
      gK += 64 * HDIM;
    }
    // issue V fragment loads for THIS tile now; consumed after softmax (~L2 hit)
    short8 vf[2][4];
#pragma unroll
    for (int kh = 0; kh < 2; ++kh)
#pragma unroll
      for (int jt = 0; jt < 4; ++jt)
        vf[kh][jt] =
            *(const short8*)&gV[(size_t)jt * 16 * SEQ + it * 64 + kh * 32];

    const unsigned short* cK = lK[it & 1];

    // mask: one 8B load per lane per tile (bit = key within 64-key tile)
    uint2 mw = *(const uint2*)&mrow[it * 2];

    // S^T: s[j][r] = logit[key = j*16 + quad*4 + r][qrow] (log2 domain)
    f32x4 s[4];
    __builtin_amdgcn_s_setprio(1);
#pragma unroll
    for (int j = 0; j < 4; ++j) {
      const char* kr = (const char*)&cK[(j * 16 + l16) * 64];
      short8 ka = *(const short8*)(kr + ((quad * 16) ^ swz));
      short8 kc = *(const short8*)(kr + ((64 + quad * 16) ^ swz));
      f32x4 z = (f32x4){0.f, 0.f, 0.f, 0.f};
      z = MFMA16(ka, qf0, z);
      z = MFMA16(kc, qf1, z);
      s[j] = z;
    }
    __builtin_amdgcn_s_setprio(0);

    unsigned int ma = mw.x >> (quad * 4);
    unsigned int mb = mw.y >> (quad * 4);
#pragma unroll
    for (int j = 0; j < 4; ++j) {
      unsigned int sel = (j < 2) ? ma : mb;
      int sh = (j & 1) << 4;
#pragma unroll
      for (int r = 0; r < 4; ++r)
        s[j][r] = (sel & (1u << (sh + r))) ? s[j][r] : -1e30f;
    }

    // tile max in v_max3 triples (feeds only the defer check)
    float a0 = fmaxf(fmaxf(s[0][0], s[0][1]), s[0][2]);
    float a1 = fmaxf(fmaxf(s[0][3], s[1][0]), s[1][1]);
    float a2 = fmaxf(fmaxf(s[1][2], s[1][3]), s[2][0]);
    float a3 = fmaxf(fmaxf(s[2][1], s[2][2]), s[2][3]);
    float a4 = fmaxf(fmaxf(s[3][0], s[3][1]), s[3][2]);
    float b0 = fmaxf(fmaxf(a0, a1), a2);
    float b1 = fmaxf(fmaxf(a3, a4), s[3][3]);
    float mx = fmaxf(b0, b1);
    mx = fmaxf(mx, __shfl_xor(mx, 16));
    mx = fmaxf(mx, __shfl_xor(mx, 32));

    // speculative P with OLD running max; raw v_exp_f32 (masked -> exp2(-inf)=0)
#pragma unroll
    for (int j = 0; j < 4; ++j)
#pragma unroll
      for (int r = 0; r < 4; ++r) s[j][r] = fexp2(s[j][r] - mi);

    if (!__all(mx <= mi + 5.f)) {    // rare: running max grew too much
      float mn = fmaxf(mi, mx);
      float al = fexp2(mi - mn);
#pragma unroll
      for (int j = 0; j < 4; ++j)
#pragma unroll
        for (int r = 0; r < 4; ++r) s[j][r] *= al;
#pragma unroll
      for (int jt = 0; jt < 4; ++jt)
#pragma unroll
        for (int r = 0; r < 4; ++r) o[jt][r] *= al;
#pragma unroll
      for (int r = 0; r < 4; ++r) li4[r] *= al;
      mi = mn;
    }

    // P -> bf16 (cvt_pk) -> LDS; 4 contiguous keys per lane -> ds_write_b64
#pragma unroll
    for (int j = 0; j < 4; ++j) {
      uint2 u;
      u.x = pk2bf(s[j][0], s[j][1]);
      u.y = pk2bf(s[j][2], s[j][3]);
      *(uint2*)((char*)lPr + ((j * 32 + quad * 8) ^ swz)) = u;
    }

    // O^T += V^T P and li += sum_k P (ones-MFMA: all output rows = denominator)
    __builtin_amdgcn_s_setprio(1);
#pragma unroll
    for (int kh = 0; kh < 2; ++kh) {
      short8 pf = *(const short8*)((const char*)lPr + ((kh * 64 + quad * 16) ^ swz));
      li4 = MFMA16(ones, pf, li4);
#pragma unroll
      for (int jt = 0; jt < 4; ++jt)
        o[jt] = MFMA16(vf[kh][jt], pf, o[jt]);
    }
    __builtin_amdgcn_s_setprio(0);
  }

  // epilogue: denominator identical in every lane/reg of li4 (division once
  // per thread -- negligible; avoids relying on rcp builtin availability)
  float inv = 1.0f / li4[0];
  int b = bh >> 4, h = bh & 15;
  unsigned short* crow = ctx + ((size_t)(b * SEQ + qrow)) * DMODEL + h * HDIM;
#pragma unroll
  for (int jt = 0; jt < 4; ++jt) {
    uint2 u;
    u.x = pk2bf(o[jt][0] * inv, o[jt][1] * inv);
    u.y = pk2bf(o[jt][2] * inv, o[jt][3] * inv);
    *(uint2*)&crow[jt * 16 + quad * 4] = u;
  }
}

// ---------------------------------------------------------------- launch
extern "C" void kernel_launch(void* const* d_in, const int* in_sizes, int n_in,
                              void* d_out, int out_size, void* d_ws, size_t ws_size,
                              hipStream_t stream) {
  const float* x = (const float*)d_in[0];
  const int* mask = (const int*)d_in[1];
  const float* w_qkv = (const float*)d_in[2];
  const float* b_qkv = (const float*)d_in[3];
  const float* w_o = (const float*)d_in[4];
  const float* b_o = (const float*)d_in[5];
  float* out = (float*)d_out;

  char* ws = (char*)d_ws;
  unsigned short* xb = (unsigned short*)(ws);                       // 8 MB
  unsigned short* wqkvb = (unsigned short*)(ws + (8ull << 20));     // 6 MB
  unsigned short* wob = (unsigned short*)(ws + (14ull << 20));      // 2 MB
  unsigned short* qb = (unsigned short*)(ws + (16ull << 20));       // 8 MB
  unsigned short* kb = (unsigned short*)(ws + (24ull << 20));       // 8 MB
  unsigned short* vtb = (unsigned short*)(ws + (32ull << 20));      // 8 MB
  unsigned short* ctx = (unsigned short*)(ws + (40ull << 20));      // 8 MB
  unsigned int* mbits = (unsigned int*)(ws + (48ull << 20));        // 512 KB

  const int na4 = (MROWS * DMODEL) / 4;
  const int nb4 = (N_QKV * DMODEL) / 4;
  const int nc4 = (DMODEL * DMODEL) / 4;
  cvt3_kernel<<<(na4 + nb4 + nc4 + 255) / 256, 256, 0, stream>>>(
      x, xb, na4, w_qkv, wqkvb, nb4, w_o, wob, nc4);
  mask_to_bits<<<512, 256, 0, stream>>>(mask, mbits);

  gemm_bt<0><<<dim3(N_QKV / 128, MROWS / 128), 256, 0, stream>>>(
      xb, wqkvb, b_qkv, DMODEL, N_QKV, qb, kb, vtb, nullptr);

  attn_kernel<<<dim3(SEQ / 64, BATCH * NHEADS), 256, 0, stream>>>(
      qb, kb, vtb, mbits, ctx);

  gemm_bt<1><<<dim3(DMODEL / 128, MROWS / 128), 256, 0, stream>>>(
      ctx, wob, b_o, DMODEL, DMODEL, nullptr, nullptr, nullptr, out);
}

// Round 5
// 233.631 us; speedup vs baseline: 1.3357x; 1.3357x over previous
//
#include <hip/hip_runtime.h>

typedef __attribute__((ext_vector_type(8))) short short8;
typedef __attribute__((ext_vector_type(4))) float f32x4;

#define MFMA16(a, b, c) __builtin_amdgcn_mfma_f32_16x16x32_bf16(a, b, c, 0, 0, 0)

// Problem constants
#define BATCH 2
#define SEQ 2048
#define DMODEL 1024
#define NHEADS 16
#define HDIM 64
#define MROWS (BATCH * SEQ)      // 4096
#define N_QKV (3 * DMODEL)       // 3072

// softmax scale 1/sqrt(64) folded with log2(e) into Q at projection time,
// so attention logits are already in the exp2 domain.
#define QSCALE 0.1803368801111184f

// global->LDS direct DMA, 16B/lane, dest = wave-uniform base + lane*16 (m97/m104)
#define GLDS16(gp, lp)                                                       \
  __builtin_amdgcn_global_load_lds(                                          \
      (const __attribute__((address_space(1))) void*)(gp),                   \
      (__attribute__((address_space(3))) void*)(lp), 16, 0, 0)

static __device__ __forceinline__ unsigned short f2bf(float f) {
  unsigned int u = __float_as_uint(f);
  u = (u + 0x7fff + ((u >> 16) & 1)) >> 16;   // round-to-nearest-even
  return (unsigned short)u;
}

static __device__ __forceinline__ unsigned int pk2bf(float lo, float hi) {
  unsigned int r;
  asm("v_cvt_pk_bf16_f32 %0, %1, %2" : "=v"(r) : "v"(lo), "v"(hi));
  return r;
}

// raw hardware exp2 (single v_exp_f32; bypasses OCML's ~12-inst range checks)
static __device__ __forceinline__ float fexp2(float x) {
  float r;
  asm("v_exp_f32 %0, %1" : "=v"(r) : "v"(x));
  return r;
}

// ---------------------------------------------------------------- cvt fp32->bf16 (x, w_qkv, w_o fused)
__global__ void cvt3_kernel(const float* __restrict__ a, unsigned short* __restrict__ oa,
                            int na4, const float* __restrict__ b,
                            unsigned short* __restrict__ ob, int nb4,
                            const float* __restrict__ c,
                            unsigned short* __restrict__ oc, int nc4) {
  int i = blockIdx.x * blockDim.x + threadIdx.x;
  const float* src;
  unsigned short* dst;
  int j = i;
  if (j < na4) {
    src = a; dst = oa;
  } else if ((j -= na4) < nb4) {
    src = b; dst = ob;
  } else if ((j -= nb4) < nc4) {
    src = c; dst = oc;
  } else
    return;
  f32x4 v = ((const f32x4*)src)[j];
  ushort4 o;
  o.x = f2bf(v[0]); o.y = f2bf(v[1]); o.z = f2bf(v[2]); o.w = f2bf(v[3]);
  ((ushort4*)dst)[j] = o;
}

// ---------------------------------------------------------------- mask -> bitmask
__global__ void mask_to_bits(const int* __restrict__ mask,
                             unsigned int* __restrict__ bits) {
  int i = blockIdx.x * blockDim.x + threadIdx.x;   // 0 .. 2048*64-1
  const int* p = mask + (size_t)i * 32;
  unsigned int v = 0;
#pragma unroll
  for (int b = 0; b < 32; ++b) v |= (p[b] != 0 ? 1u : 0u) << b;
  bits[i] = v;
}

// ---------------------------------------------------------------- NT GEMM, 128x128 tile
// C[M,N] = A[M,K] * B[N,K]^T + bias[N]
template <int EPI>
__global__ __launch_bounds__(256) void gemm_bt(
    const unsigned short* __restrict__ A, const unsigned short* __restrict__ Bm,
    const float* __restrict__ bias, int Kdim, int Ndim,
    unsigned short* __restrict__ qb, unsigned short* __restrict__ kb,
    unsigned short* __restrict__ vtb, float* __restrict__ Cout) {
  __shared__ __align__(16) unsigned short lA[128 * 40];
  __shared__ __align__(16) unsigned short lB[128 * 40];

  int t = threadIdx.x;
  int m0 = blockIdx.y * 128, n0 = blockIdx.x * 128;
  int w = t >> 6, lane = t & 63, quad = lane >> 4, l16 = lane & 15;
  int wm = (w >> 1) * 64, wn = (w & 1) * 64;

  f32x4 acc[4][4];
#pragma unroll
  for (int i = 0; i < 4; ++i)
#pragma unroll
    for (int j = 0; j < 4; ++j) acc[i][j] = (f32x4){0.f, 0.f, 0.f, 0.f};

  int nK = Kdim >> 5;
  for (int kk = 0; kk < nK; ++kk) {
    __syncthreads();
#pragma unroll
    for (int c = 0; c < 2; ++c) {
      int id = t + c * 256;
      int row = id >> 2, c8 = (id & 3) << 3;
      *(uint4*)&lA[row * 40 + c8] =
          *(const uint4*)&A[(size_t)(m0 + row) * Kdim + (kk << 5) + c8];
      *(uint4*)&lB[row * 40 + c8] =
          *(const uint4*)&Bm[(size_t)(n0 + row) * Kdim + (kk << 5) + c8];
    }
    __syncthreads();
    short8 af[4], bfr[4];
#pragma unroll
    for (int i = 0; i < 4; ++i)
      af[i] = *(const short8*)&lA[(wm + i * 16 + l16) * 40 + quad * 8];
#pragma unroll
    for (int j = 0; j < 4; ++j)
      bfr[j] = *(const short8*)&lB[(wn + j * 16 + l16) * 40 + quad * 8];
#pragma unroll
    for (int i = 0; i < 4; ++i)
#pragma unroll
      for (int j = 0; j < 4; ++j) acc[i][j] = MFMA16(af[i], bfr[j], acc[i][j]);
  }

#pragma unroll
  for (int j = 0; j < 4; ++j) {
    int n = n0 + wn + j * 16 + l16;
    float bs = bias[n];
#pragma unroll
    for (int i = 0; i < 4; ++i) {
#pragma unroll
      for (int r = 0; r < 4; ++r) {
        int m = m0 + wm + i * 16 + quad * 4 + r;
        float v = acc[i][j][r] + bs;
        if (EPI == 0) {
          int b = m >> 11, s = m & 2047;
          int h = n / 192, rr = n % 192;
          int bh = (b << 4) + h;
          if (rr < 64)
            qb[((size_t)bh * SEQ + s) * HDIM + rr] = f2bf(v * QSCALE);
          else if (rr < 128)
            kb[((size_t)bh * SEQ + s) * HDIM + (rr - 64)] = f2bf(v);
          else
            vtb[((size_t)bh * HDIM + (rr - 128)) * SEQ + s] = f2bf(v);
        } else {
          Cout[(size_t)m * Ndim + n] = v;
        }
      }
    }
  }
}

// ---------------------------------------------------------------- flash attention
// grid: 1024 blocks (32 q-tiles of 64 rows x 32 bh), block 256 = 4 waves; wave
// owns 16 q-rows. Swapped-operand scheme: S^T = mfma(K, Q), O^T = mfma(V^T, P)
// so per-q-row softmax state lives at lane l16 (2 shfls per tile total).
// Round-2 memory structure (K AND V LDS-staged via global_load_lds, XOR-swizzled
// source, double-buffered, ONE barrier per tile — latency proven hidden at 91us)
// + round-4 VALU diet (raw v_exp_f32, ones-MFMA denominator, max3 tree,
// speculative defer-max). V-from-L2 (r4) reverted: it serialized a vmcnt(0)
// drain + 16-line uncoalesced V loads into every tile (156us regression).
__global__ __launch_bounds__(256, 4) void attn_kernel(
    const unsigned short* __restrict__ qbuf, const unsigned short* __restrict__ kbuf,
    const unsigned short* __restrict__ vtbuf, const unsigned int* __restrict__ mbits,
    unsigned short* __restrict__ ctx) {
  __shared__ __align__(16) unsigned short lK[2][64 * 64];
  __shared__ __align__(16) unsigned short lV[2][64 * 64];   // V^T: [d][key]
  __shared__ __align__(16) unsigned short lP[64 * 64];      // [q][key], per-wave rows

  // XCD-aware swizzle: cluster the 32 q-tiles of ~4 bh per XCD (1024 = 8*128)
  int lin = blockIdx.y * gridDim.x + blockIdx.x;
  int slin = (lin & 7) * 128 + (lin >> 3);
  int qt = slin & 31, bh = slin >> 5;
  int q0 = qt * 64;
  const unsigned short* Q = qbuf + (size_t)bh * SEQ * HDIM;
  const unsigned short* K = kbuf + (size_t)bh * SEQ * HDIM;
  const unsigned short* VT = vtbuf + (size_t)bh * HDIM * SEQ;

  int t = threadIdx.x;
  int w = t >> 6, lane = t & 63, quad = lane >> 4, l16 = lane & 15;
  int swz = (l16 & 7) << 4;          // byte-XOR swizzle for rows this lane reads

  // Q fragments in registers (scale*log2e pre-folded at projection)
  int qrow = q0 + w * 16 + l16;      // 0..2047
  short8 qf0 = *(const short8*)&Q[(size_t)qrow * HDIM + quad * 8];
  short8 qf1 = *(const short8*)&Q[(size_t)qrow * HDIM + 32 + quad * 8];

  // all-ones bf16 A-operand for the denominator MFMA
  const short one = (short)0x3F80;
  short8 ones = {one, one, one, one, one, one, one, one};

  f32x4 o[4];
#pragma unroll
  for (int jt = 0; jt < 4; ++jt) o[jt] = (f32x4){0.f, 0.f, 0.f, 0.f};
  f32x4 li4 = (f32x4){0.f, 0.f, 0.f, 0.f};   // all 4 regs == running denom
  // mi=0 is safe: logits ~ N(0, ~1.2) in log2 domain; exp2(s-0) can't overflow.
  float mi = 0.f;

  // staging: wave w stages rows {w*8..w*8+7, 32+w*8..}; global col pre-swizzled
  // so the linear LDS dest ends up XOR-swizzled (m173).
  int scol = ((lane & 7) ^ (lane >> 3)) << 3;   // shorts; srow&7 == lane>>3
  const unsigned short* gK = K + (size_t)(w * 8 + (lane >> 3)) * HDIM + scol;
  const unsigned short* gV = VT + (size_t)(w * 8 + (lane >> 3)) * SEQ + scol;

#define STAGE_KV(buf)                                            \
  do {                                                           \
    GLDS16(gK, &lK[buf][(w * 8) * 64]);                          \
    GLDS16(gK + 32 * HDIM, &lK[buf][(32 + w * 8) * 64]);         \
    GLDS16(gV, &lV[buf][(w * 8) * 64]);                          \
    GLDS16(gV + 32 * SEQ, &lV[buf][(32 + w * 8) * 64]);          \
  } while (0)

  STAGE_KV(0);
  gK += 64 * HDIM;
  gV += 64;

  const unsigned int* mrow = mbits + (size_t)qrow * 64;
  unsigned short* lPr = &lP[(w * 16 + l16) * 64];

  for (int it = 0; it < SEQ / 64; ++it) {
    __syncthreads();   // drains vmcnt -> tile `it` staged; prev reads done
    if (it + 1 < SEQ / 64) {         // prefetch next tile into other half
      STAGE_KV((it + 1) & 1);
      gK += 64 * HDIM;
      gV += 64;
    }
    const unsigned short* cK = lK[it & 1];
    const unsigned short* cV = lV[it & 1];

    // mask: one 8B load per lane per tile (bit = key within 64-key tile)
    uint2 mw = *(const uint2*)&mrow[it * 2];

    // S^T: s[j][r] = logit[key = j*16 + quad*4 + r][qrow] (log2 domain)
    f32x4 s[4];
    __builtin_amdgcn_s_setprio(1);
#pragma unroll
    for (int j = 0; j < 4; ++j) {
      const char* kr = (const char*)&cK[(j * 16 + l16) * 64];
      short8 ka = *(const short8*)(kr + ((quad * 16) ^ swz));
      short8 kc = *(const short8*)(kr + ((64 + quad * 16) ^ swz));
      f32x4 z = (f32x4){0.f, 0.f, 0.f, 0.f};
      z = MFMA16(ka, qf0, z);
      z = MFMA16(kc, qf1, z);
      s[j] = z;
    }
    __builtin_amdgcn_s_setprio(0);

    unsigned int ma = mw.x >> (quad * 4);
    unsigned int mb = mw.y >> (quad * 4);
#pragma unroll
    for (int j = 0; j < 4; ++j) {
      unsigned int sel = (j < 2) ? ma : mb;
      int sh = (j & 1) << 4;
#pragma unroll
      for (int r = 0; r < 4; ++r)
        s[j][r] = (sel & (1u << (sh + r))) ? s[j][r] : -1e30f;
    }

    // tile max in v_max3 triples (feeds only the defer check)
    float a0 = fmaxf(fmaxf(s[0][0], s[0][1]), s[0][2]);
    float a1 = fmaxf(fmaxf(s[0][3], s[1][0]), s[1][1]);
    float a2 = fmaxf(fmaxf(s[1][2], s[1][3]), s[2][0]);
    float a3 = fmaxf(fmaxf(s[2][1], s[2][2]), s[2][3]);
    float a4 = fmaxf(fmaxf(s[3][0], s[3][1]), s[3][2]);
    float b0 = fmaxf(fmaxf(a0, a1), a2);
    float b1 = fmaxf(fmaxf(a3, a4), s[3][3]);
    float mx = fmaxf(b0, b1);
    mx = fmaxf(mx, __shfl_xor(mx, 16));
    mx = fmaxf(mx, __shfl_xor(mx, 32));

    // speculative P with OLD running max; raw v_exp_f32 (masked -> exp2(-inf)=0)
#pragma unroll
    for (int j = 0; j < 4; ++j)
#pragma unroll
      for (int r = 0; r < 4; ++r) s[j][r] = fexp2(s[j][r] - mi);

    if (!__all(mx <= mi + 5.f)) {    // rare: running max grew too much
      float mn = fmaxf(mi, mx);
      float al = fexp2(mi - mn);
#pragma unroll
      for (int j = 0; j < 4; ++j)
#pragma unroll
        for (int r = 0; r < 4; ++r) s[j][r] *= al;
#pragma unroll
      for (int jt = 0; jt < 4; ++jt)
#pragma unroll
        for (int r = 0; r < 4; ++r) o[jt][r] *= al;
#pragma unroll
      for (int r = 0; r < 4; ++r) li4[r] *= al;
      mi = mn;
    }

    // P -> bf16 (cvt_pk) -> LDS; 4 contiguous keys per lane -> ds_write_b64
#pragma unroll
    for (int j = 0; j < 4; ++j) {
      uint2 u;
      u.x = pk2bf(s[j][0], s[j][1]);
      u.y = pk2bf(s[j][2], s[j][3]);
      *(uint2*)((char*)lPr + ((j * 32 + quad * 8) ^ swz)) = u;
    }

    // O^T += V^T P and li += sum_k P (ones-MFMA: all output rows = denominator)
    __builtin_amdgcn_s_setprio(1);
#pragma unroll
    for (int kh = 0; kh < 2; ++kh) {
      short8 pf = *(const short8*)((const char*)lPr + ((kh * 64 + quad * 16) ^ swz));
      li4 = MFMA16(ones, pf, li4);
#pragma unroll
      for (int jt = 0; jt < 4; ++jt) {
        const char* vr = (const char*)&cV[(jt * 16 + l16) * 64];
        short8 vf = *(const short8*)(vr + ((kh * 64 + quad * 16) ^ swz));
        o[jt] = MFMA16(vf, pf, o[jt]);
      }
    }
    __builtin_amdgcn_s_setprio(0);
  }

  // epilogue: denominator identical in every lane/reg of li4
  float inv = 1.0f / li4[0];
  int b = bh >> 4, h = bh & 15;
  unsigned short* crow = ctx + ((size_t)(b * SEQ + qrow)) * DMODEL + h * HDIM;
#pragma unroll
  for (int jt = 0; jt < 4; ++jt) {
    uint2 u;
    u.x = pk2bf(o[jt][0] * inv, o[jt][1] * inv);
    u.y = pk2bf(o[jt][2] * inv, o[jt][3] * inv);
    *(uint2*)&crow[jt * 16 + quad * 4] = u;
  }
}

// ---------------------------------------------------------------- launch
extern "C" void kernel_launch(void* const* d_in, const int* in_sizes, int n_in,
                              void* d_out, int out_size, void* d_ws, size_t ws_size,
                              hipStream_t stream) {
  const float* x = (const float*)d_in[0];
  const int* mask = (const int*)d_in[1];
  const float* w_qkv = (const float*)d_in[2];
  const float* b_qkv = (const float*)d_in[3];
  const float* w_o = (const float*)d_in[4];
  const float* b_o = (const float*)d_in[5];
  float* out = (float*)d_out;

  char* ws = (char*)d_ws;
  unsigned short* xb = (unsigned short*)(ws);                       // 8 MB
  unsigned short* wqkvb = (unsigned short*)(ws + (8ull << 20));     // 6 MB
  unsigned short* wob = (unsigned short*)(ws + (14ull << 20));      // 2 MB
  unsigned short* qb = (unsigned short*)(ws + (16ull << 20));       // 8 MB
  unsigned short* kb = (unsigned short*)(ws + (24ull << 20));       // 8 MB
  unsigned short* vtb = (unsigned short*)(ws + (32ull << 20));      // 8 MB
  unsigned short* ctx = (unsigned short*)(ws + (40ull << 20));      // 8 MB
  unsigned int* mbits = (unsigned int*)(ws + (48ull << 20));        // 512 KB

  const int na4 = (MROWS * DMODEL) / 4;
  const int nb4 = (N_QKV * DMODEL) / 4;
  const int nc4 = (DMODEL * DMODEL) / 4;
  cvt3_kernel<<<(na4 + nb4 + nc4 + 255) / 256, 256, 0, stream>>>(
      x, xb, na4, w_qkv, wqkvb, nb4, w_o, wob, nc4);
  mask_to_bits<<<512, 256, 0, stream>>>(mask, mbits);

  gemm_bt<0><<<dim3(N_QKV / 128, MROWS / 128), 256, 0, stream>>>(
      xb, wqkvb, b_qkv, DMODEL, N_QKV, qb, kb, vtb, nullptr);

  attn_kernel<<<dim3(SEQ / 64, BATCH * NHEADS), 256, 0, stream>>>(
      qb, kb, vtb, mbits, ctx);

  gemm_bt<1><<<dim3(DMODEL / 128, MROWS / 128), 256, 0, stream>>>(
      ctx, wob, b_o, DMODEL, DMODEL, nullptr, nullptr, nullptr, out);
}